// Round 18
// baseline (114.295 us; speedup 1.0000x reference)
//
#include <hip/hip_runtime.h>

#define NM    20
#define NP1   21
#define NPAIR 441
#define RECF  276            // floats per point record: 231 Q (n-major tri) + pad + 21 W pairs at 232+2m
#define RECQ4 (RECF / 4)     // 69 f32x4

typedef float f32x4 __attribute__((ext_vector_type(4)));
typedef float f32x2 __attribute__((ext_vector_type(2)));

struct Tbl {
    float dprod[NP1];
    float e[NP1];
    float a[NP1][NP1];
    float b[NP1][NP1];
};

constexpr double csqrt_d(double x) {
    double r = x * 0.5 + 0.5;
    for (int i = 0; i < 48; ++i) r = 0.5 * (r + x / r);
    return r;
}

constexpr Tbl make_tbl() {
    Tbl t{};
    const double inv4pi = 0.28209479177387814;
    double dp = inv4pi;
    t.dprod[0] = (float)dp;
    for (int m = 1; m <= NM; ++m) {
        dp *= -csqrt_d((2.0 * m + 1.0) / (2.0 * m));
        t.dprod[m] = (float)dp;
    }
    for (int m = 0; m <= NM; ++m) t.e[m] = (float)csqrt_d(2.0 * m + 3.0);
    for (int m = 0; m <= NM; ++m)
        for (int n = m + 2; n <= NM; ++n) {
            double nn = (double)n * n, mm = (double)m * m;
            t.a[m][n] = (float)csqrt_d((4.0 * nn - 1.0) / (nn - mm));
            t.b[m][n] = (float)csqrt_d((2.0 * n + 1.0) * (n - 1.0 - m) * (n - 1.0 + m) /
                                       ((2.0 * n - 3.0) * (nn - mm)));
        }
    return t;
}
__constant__ Tbl TBL = make_tbl();

// Channel-pair metadata: pidx(8b, n-major tri: n(n+1)/2+am) | am<<8 | negRe<<13 | negIm<<14
struct CMap { unsigned short m[448]; };
constexpr CMap make_cmap() {
    CMap c{};
    int ch = 0;
    for (int n = 0; n <= NM; ++n)
        for (int mm = -n; mm <= n; ++mm) {
            int am = mm < 0 ? -mm : mm;
            unsigned pidx = (unsigned)(n * (n + 1) / 2 + am);
            unsigned negRe = (mm < 0 && (am & 1)) ? 1u : 0u;
            unsigned negIm = (mm < 0 && !(am & 1)) ? 1u : 0u;
            c.m[ch++] = (unsigned short)(pidx | (am << 8) | (negRe << 13) | (negIm << 14));
        }
    return c;
}
__constant__ CMap CMAP = make_cmap();

__device__ __forceinline__ void sincos_small(float t, float& sn, float& cs) {
    const float t2 = t * t;
    sn = t * (1.0f + t2 * (-1.0f/6.0f + t2 * (1.0f/120.0f + t2 * (-1.0f/5040.0f))));
    cs = 1.0f + t2 * (-0.5f + t2 * (1.0f/24.0f + t2 * (-1.0f/720.0f + t2 * (1.0f/40320.0f))));
}

// Shared phase-1 math: lane computes m-column of point; returns via LDS writes.
__device__ __forceinline__ void compute_point_col(float th, float ph, int m, float* rec) {
    float st, ct, s, x;
    sincos_small(th, st, ct);              // e^{i*theta}
    sincos_small(ph, s, x);                // s = sin(phi), x = cos(phi)
    float wc = 1.0f, ws = 0.0f;            // W = (s e^{i th})^m
    float bc = s * ct, bs = s * st;
    int mb = m;
    #pragma unroll
    for (int i = 0; i < 5; ++i) {
        const float nwc = wc * bc - ws * bs;
        const float nws = wc * bs + ws * bc;
        wc = (mb & 1) ? nwc : wc;
        ws = (mb & 1) ? nws : ws;
        mb >>= 1;
        const float t = bc * bc - bs * bs;
        bs = 2.0f * bc * bs;
        bc = t;
    }
    *reinterpret_cast<float2*>(rec + 232 + 2 * m) = make_float2(wc, ws);
    float qb = 0.0f, qa = TBL.dprod[m];    // Q = P / s^m
    for (int n = m; n <= NM; ++n) {
        rec[n * (n + 1) / 2 + m] = qa;     // n-major triangle
        if (n < NM) {
            const float qn = (n == m) ? TBL.e[m] * x * qa
                                      : TBL.a[m][n + 1] * x * qa - TBL.b[m][n + 1] * qb;
            qb = qa; qa = qn;
        }
    }
}

// ---- Kernel 1: compact records (Q-triangle + W) -> workspace, PLAIN stores (stay cached)
#define K1PTS 4
#define K1BLK 128
__global__ __launch_bounds__(K1BLK) void k1_compute(const float* __restrict__ theta,
                                                    const float* __restrict__ phi,
                                                    float* __restrict__ ws_, int npts) {
    __shared__ __align__(16) float sh[K1PTS][RECF];
    const int tid = threadIdx.x;
    const int pt  = tid >> 5;
    const int col = tid & 31;
    const int gpt0 = blockIdx.x * K1PTS;
    const int gpt  = gpt0 + pt;
    if (gpt < npts && col <= NM)
        compute_point_col(theta[gpt], phi[gpt], col, sh[pt]);
    __syncthreads();
    // coalesced copy: 4 * 69 = 276 f32x4
    const int nv = (min(K1PTS, npts - gpt0)) * RECQ4;
    const f32x4* __restrict__ src = reinterpret_cast<const f32x4*>(&sh[0][0]);
    f32x4* __restrict__ dst = reinterpret_cast<f32x4*>(ws_) + (long long)gpt0 * RECQ4;
    for (int k = tid; k < nv; k += K1BLK) dst[k] = src[k];
}

// ---- Kernel 2: probeA-shaped expansion. Long-lived 256-thr blocks, no LDS, no
// barriers; per wave: 8 contiguous points; per point: 7 sweeps of (2 gathers
// from L2/L3-resident record + 2 muls + sign XOR + coalesced nt f32x2 store).
#define K2BLK 256
#define K2GRID 2048
__global__ __launch_bounds__(K2BLK) void k2_expand(const float* __restrict__ ws_,
                                                   float* __restrict__ out,
                                                   int npts, int ppw) {
    const int lane = threadIdx.x & 63;
    const int gw   = (blockIdx.x * K2BLK + threadIdx.x) >> 6;   // global wave id
    unsigned em[7];
    #pragma unroll
    for (int i = 0; i < 7; ++i) em[i] = CMAP.m[i * 64 + lane];

    const int p0 = gw * ppw;
    #pragma unroll 1
    for (int k = 0; k < ppw; ++k) {
        const int p = p0 + k;
        if (p >= npts) break;
        const float* __restrict__ rec = ws_ + (long long)p * RECF;
        f32x2* __restrict__ dst = reinterpret_cast<f32x2*>(out) + (long long)p * NPAIR;
        #pragma unroll
        for (int i = 0; i < 7; ++i) {
            if (i < 6 || lane < NPAIR - 384) {
                const unsigned e = em[i];
                const float Q = rec[e & 255u];
                const int am  = (e >> 8) & 31u;
                const float2 w = *reinterpret_cast<const float2*>(rec + 232 + 2 * am);
                float re = Q * w.x, im = Q * w.y;
                re = __uint_as_float(__float_as_uint(re) ^ (((e >> 13) & 1u) << 31));
                im = __uint_as_float(__float_as_uint(im) ^ (((e >> 14) & 1u) << 31));
                __builtin_nontemporal_store(f32x2{re, im}, dst + i * 64 + lane);
            }
        }
    }
}

// ---- Fallback: R9/R15 champion (fused), if ws_size too small ----
#define ROWF  882
#define BLKF  (K1PTS * ROWF)
#define BLKF4 (BLKF / 4)
__global__ __launch_bounds__(K1BLK) void sph_fused(const float* __restrict__ theta,
                                                   const float* __restrict__ phi,
                                                   float* __restrict__ out, int npts) {
    __shared__ __align__(16) float sh[K1PTS][ROWF];
    const int tid = threadIdx.x;
    const int pt  = tid >> 5;
    const int col = tid & 31;
    const int gpt0 = blockIdx.x * K1PTS;
    const int gpt  = gpt0 + pt;
    if (gpt < npts && col <= NM) {
        const float th = theta[gpt], ph = phi[gpt];
        float st, ct, s, x;
        sincos_small(th, st, ct);
        sincos_small(ph, s, x);
        float* row = sh[pt];
        const int m = col;
        float wc = 1.0f, ws = 0.0f, bc = s * ct, bs = s * st;
        int mb = m;
        #pragma unroll
        for (int i = 0; i < 5; ++i) {
            const float nwc = wc * bc - ws * bs, nws = wc * bs + ws * bc;
            wc = (mb & 1) ? nwc : wc; ws = (mb & 1) ? nws : ws; mb >>= 1;
            const float t = bc * bc - bs * bs; bs = 2.0f * bc * bs; bc = t;
        }
        const float wcn = (m & 1) ? -wc : wc, wsn = (m & 1) ? ws : -ws;
        float qb = 0.0f, qa = TBL.dprod[m];
        int nn = m * (m + 1);
        for (int n = m; n <= NM; ++n) {
            *reinterpret_cast<float2*>(row + 2 * (nn + m)) = make_float2(qa * wc, qa * ws);
            if (m > 0)
                *reinterpret_cast<float2*>(row + 2 * (nn - m)) = make_float2(qa * wcn, qa * wsn);
            if (n < NM) {
                const float qn = (n == m) ? TBL.e[m] * x * qa
                                          : TBL.a[m][n + 1] * x * qa - TBL.b[m][n + 1] * qb;
                qb = qa; qa = qn;
            }
            nn += 2 * (n + 1);
        }
    }
    __syncthreads();
    const long long base = (long long)blockIdx.x * BLKF;
    if (gpt0 + K1PTS <= npts) {
        const f32x4* __restrict__ src = reinterpret_cast<const f32x4*>(&sh[0][0]);
        f32x4* __restrict__ dst = reinterpret_cast<f32x4*>(out + base);
        #pragma unroll
        for (int k = 0; k < BLKF4 / K1BLK; ++k)
            __builtin_nontemporal_store(src[tid + k * K1BLK], dst + tid + k * K1BLK);
        const int j = tid + (BLKF4 / K1BLK) * K1BLK;
        if (j < BLKF4) __builtin_nontemporal_store(src[j], dst + j);
    } else {
        const int vpts = npts - gpt0;
        if (vpts > 0) {
            const f32x2* __restrict__ src = reinterpret_cast<const f32x2*>(&sh[0][0]);
            f32x2* __restrict__ dst = reinterpret_cast<f32x2*>(out + base);
            for (int j = tid; j < vpts * (ROWF / 2); j += K1BLK)
                __builtin_nontemporal_store(src[j], dst + j);
        }
    }
}

extern "C" void kernel_launch(void* const* d_in, const int* in_sizes, int n_in,
                              void* d_out, int out_size, void* d_ws, size_t ws_size,
                              hipStream_t stream) {
    const float* theta = (const float*)d_in[0];
    const float* phi   = (const float*)d_in[1];
    float* out = (float*)d_out;
    const int npts = in_sizes[0];
    const size_t need = (size_t)npts * RECF * sizeof(float);   // 72.3 MB at 65536 pts

    if (ws_size >= need) {
        float* wsp = (float*)d_ws;
        const int blocks1 = (npts + K1PTS - 1) / K1PTS;
        k1_compute<<<blocks1, K1BLK, 0, stream>>>(theta, phi, wsp, npts);
        const int nwaves = K2GRID * (K2BLK / 64);
        const int ppw = (npts + nwaves - 1) / nwaves;          // 8 at 65536
        k2_expand<<<K2GRID, K2BLK, 0, stream>>>(wsp, out, npts, ppw);
    } else {
        const int blocks = (npts + K1PTS - 1) / K1PTS;
        sph_fused<<<blocks, K1BLK, 0, stream>>>(theta, phi, out, npts);
    }
}